// Round 18
// baseline (118.051 us; speedup 1.0000x reference)
//
#include <hip/hip_runtime.h>
#include <stdint.h>

#define B_ 4
#define T_ 2048
#define S_ 2048
#define E_ 512
#define H_ 8
#define D_ 64

using bf16x8 = __attribute__((ext_vector_type(8))) short;
using bf16x4 = __attribute__((ext_vector_type(4))) short;
using f32x4  = __attribute__((ext_vector_type(4))) float;

__device__ __forceinline__ unsigned short f2bf(float f) {
  unsigned u = __float_as_uint(f);
  u += 0x7fffu + ((u >> 16) & 1u);          // round-to-nearest-even
  return (unsigned short)(u >> 16);
}

__device__ __forceinline__ float sigmoidf_(float x) {
  return 1.0f / (1.0f + __expf(-x));
}

// 8 fp32 -> 8 bf16 packed in a uint4, via HW packed converts
__device__ __forceinline__ uint4 cvt8(float4 a, float4 b) {
  uint4 r;
  asm("v_cvt_pk_bf16_f32 %0, %1, %2" : "=v"(r.x) : "v"(a.x), "v"(a.y));
  asm("v_cvt_pk_bf16_f32 %0, %1, %2" : "=v"(r.y) : "v"(a.z), "v"(a.w));
  asm("v_cvt_pk_bf16_f32 %0, %1, %2" : "=v"(r.z) : "v"(b.x), "v"(b.y));
  asm("v_cvt_pk_bf16_f32 %0, %1, %2" : "=v"(r.w) : "v"(b.z), "v"(b.w));
  return r;
}

// legacy K=16 bf16 MFMA: A/B = 4 bf16 (2 VGPR), layout row=lane&15, k=(lane>>4)*4+e
__device__ __forceinline__ f32x4 mfma16x16x16(bf16x4 a, bf16x4 b, f32x4 c) {
#if __has_builtin(__builtin_amdgcn_mfma_f32_16x16x16bf16_1k)
  return __builtin_amdgcn_mfma_f32_16x16x16bf16_1k(a, b, c, 0, 0, 0);
#else
  asm("v_mfma_f32_16x16x16_bf16 %0, %1, %2, %0" : "+v"(c) : "v"(a), "v"(b));
  return c;
#endif
}

// async global->LDS, 16B per lane. LDS dest = wave-uniform base + lane*16.
__device__ __forceinline__ void gl16(const void* g, void* l) {
  __builtin_amdgcn_global_load_lds(
      (const __attribute__((address_space(1))) unsigned*)g,
      (__attribute__((address_space(3))) unsigned*)l,
      16, 0, 0);
}

// T2 swizzle for [R][64 bf16] (128B-row) LDS tiles:
// physical byte-in-row = logical byte-in-row ^ ((row&7)<<4).
__device__ __forceinline__ int swzi(int row, int ebyte) {
  return row * 64 + ((ebyte ^ ((row & 7) << 4)) >> 1);
}

// ---------------------------------------------------------------- merged projection GEMMs
// One launch, 1536 blocks (512/job, 128x64 tiles). fp32 operands, fused cvt
// staging. 2-DEEP register pipeline: LOAD(kt+2) issued at step kt, WRITE(kt+1)
// at end of step kt from registers loaded a FULL step earlier (~600-800cy
// load-use distance covers L2/HBM latency; R17's 1-step distance exposed it).
// job 0: C=logistic(query Wq^T+bq)*sclq -> [B,H,T,D]
// job 1: C=logistic(key  Wk^T+bk)      -> [B,H,S,D]
// job 2: C=(Wv value^T+bv)             -> [B,H,D,S]   (A=Wv, W=value)
__global__ __launch_bounds__(256) void gemm_proj(
    const float* __restrict__ Aq, const float* __restrict__ Wqf,
    const float* __restrict__ bqp, unsigned short* __restrict__ oq,
    const float* __restrict__ Ak, const float* __restrict__ Wkf,
    const float* __restrict__ bkp, unsigned short* __restrict__ ok,
    const float* __restrict__ Wvf, const float* __restrict__ Av,
    const float* __restrict__ bvp, unsigned short* __restrict__ ov,
    const float* __restrict__ rptr, float sclq) {
  __shared__ unsigned short As[2][128 * 64];   // 32 KB
  __shared__ unsigned short Bs[2][64 * 64];    // 16 KB

  int job = blockIdx.x >> 9;                     // 0,1,2 (uniform per block)
  int x = blockIdx.x & 511;
  int bid = ((x & 7) << 6) + (x >> 3);           // XCD-bijective within job
  const float* A = (job == 0) ? Aq : (job == 1) ? Ak : Wvf;
  const float* W = (job == 0) ? Wqf : (job == 1) ? Wkf : Av;
  const float* bias = (job == 0) ? bqp : (job == 1) ? bkp : bvp;
  unsigned short* outp = (job == 0) ? oq : (job == 1) ? ok : ov;

  int bm, bn;
  if (job == 2) { bm = bid >> 7; bn = bid & 127; }   // M=512 (e), N=8192 (b*s)
  else          { bm = bid >> 3; bn = bid & 7; }     // M=8192, N=512
  int m0 = bm * 128, n0 = bn * 64;

  f32x4 acc[4][2] = {};

  int tid = threadIdx.x;
  int lane = tid & 63, wid = tid >> 6;
  int rowc = tid >> 3, slot = tid & 7;
  int fcol = (slot ^ (rowc & 7)) << 3;            // pre-swizzled fp32 col (8 floats)

  // two in-flight register sets (all statically indexed)
  float4 la[8], lb[4];   // set a: even-future steps
  float4 ma[8], mb[4];   // set b: odd-future steps

#define PLOAD(LA, LB, KT) { \
    _Pragma("unroll") \
    for (int c = 0; c < 4; ++c) { \
      const float* g = A + (size_t)(m0 + c * 32 + rowc) * 512 + (KT) * 64 + fcol; \
      LA[c * 2] = *(const float4*)g; \
      LA[c * 2 + 1] = *(const float4*)(g + 4); \
    } \
    _Pragma("unroll") \
    for (int c = 0; c < 2; ++c) { \
      const float* g = W + (size_t)(n0 + c * 32 + rowc) * 512 + (KT) * 64 + fcol; \
      LB[c * 2] = *(const float4*)g; \
      LB[c * 2 + 1] = *(const float4*)(g + 4); \
    } }
#define PWRITE(LA, LB, BUF) { \
    _Pragma("unroll") \
    for (int c = 0; c < 4; ++c) \
      *(uint4*)((char*)&As[BUF][0] + c * 4096 + rowc * 128 + slot * 16) = \
          cvt8(LA[c * 2], LA[c * 2 + 1]); \
    _Pragma("unroll") \
    for (int c = 0; c < 2; ++c) \
      *(uint4*)((char*)&Bs[BUF][0] + c * 4096 + rowc * 128 + slot * 16) = \
          cvt8(LB[c * 2], LB[c * 2 + 1]); }

  int wm = wid >> 1, wn = wid & 1;       // 2x2 waves; each wave 64(M) x 32(N)
  int fr = lane & 15, fg = lane >> 4;

#define PMFMA(BUF) { \
    _Pragma("unroll") \
    for (int ks = 0; ks < 2; ++ks) { \
      bf16x8 a[4], b[2]; \
      _Pragma("unroll") \
      for (int mi = 0; mi < 4; ++mi) \
        a[mi] = *(const bf16x8*)&As[BUF][swzi(wm * 64 + mi * 16 + fr, ks * 64 + fg * 16)]; \
      _Pragma("unroll") \
      for (int ni = 0; ni < 2; ++ni) \
        b[ni] = *(const bf16x8*)&Bs[BUF][swzi(wn * 32 + ni * 16 + fr, ks * 64 + fg * 16)]; \
      _Pragma("unroll") \
      for (int mi = 0; mi < 4; ++mi) \
        _Pragma("unroll") \
        for (int ni = 0; ni < 2; ++ni) \
          acc[mi][ni] = __builtin_amdgcn_mfma_f32_16x16x32_bf16(a[mi], b[ni], acc[mi][ni], 0, 0, 0); \
    } }

  // prologue: buf0 <- kt0 (immediate); set b <- kt1 (in flight)
  PLOAD(la, lb, 0)
  PWRITE(la, lb, 0)
  PLOAD(ma, mb, 1)

#pragma unroll 1
  for (int p = 0; p < 8; p += 2) {
    // ---- step p (reads buf0)
    __syncthreads();                       // buf0 ready for ALL waves
    if (p + 2 < 8) PLOAD(la, lb, p + 2)    // set a free; data for step p+2
    PMFMA(0)
    PWRITE(ma, mb, 1)                      // kt=p+1, loaded a full step ago
    // ---- step p+1 (reads buf1)
    __syncthreads();                       // buf1 ready
    if (p + 3 < 8) PLOAD(ma, mb, p + 3)
    PMFMA(1)
    if (p + 2 < 8) PWRITE(la, lb, 0)       // kt=p+2, loaded a full step ago
  }

  float rs = 4.0f * sigmoidf_(rptr[0]) * ((job == 0) ? sclq : 1.0f);

#pragma unroll
  for (int mi = 0; mi < 4; ++mi) {
#pragma unroll
    for (int ni = 0; ni < 2; ++ni) {
#pragma unroll
      for (int i = 0; i < 4; ++i) {
        int gm = m0 + wm * 64 + mi * 16 + fg * 4 + i;   // C row
        int gn = n0 + wn * 32 + ni * 16 + fr;           // C col
        float v = acc[mi][ni][i];
        if (job < 2) {
          v += bias[gn];
          float xn = sigmoidf_(v);
          float val = rs * xn * (1.0f - xn);
          int b = gm >> 11, t = gm & 2047, h = gn >> 6, d = gn & 63;
          outp[((size_t)(b * H_ + h) * T_ + t) * D_ + d] = f2bf(val);
        } else {
          v += bias[gm];                                // bias indexed by e = row
          int h = gm >> 6, d = gm & 63, b = gn >> 11, s = gn & 2047;
          outp[((size_t)(b * H_ + h) * D_ + d) * S_ + s] = f2bf(v);
        }
      }
    }
  }
#undef PLOAD
#undef PWRITE
#undef PMFMA
}

// ---------------------------------------------------------------- GEMM (output proj)
// C = attno(bf16, gl16-staged) x Wo(fp32, reg-staged+cvt)^T + bo, fp32 out.
__global__ __launch_bounds__(256) void gemm_out(
    const unsigned short* __restrict__ A,
    const float* __restrict__ Wf,
    const float* __restrict__ bias,
    float* __restrict__ outp) {
  __shared__ unsigned short As[2][128 * 64];   // 32 KB
  __shared__ unsigned short Bs[2][64 * 64];    // 16 KB

  int bid = ((blockIdx.x & 7) << 6) + (blockIdx.x >> 3);  // 512 blocks, 8 XCDs
  int tid = threadIdx.x;
  int lane = tid & 63, wid = tid >> 6;
  int bm = bid >> 3, bn = bid & 7;
  int m0 = bm * 128, n0 = bn * 64;

  f32x4 acc[4][2] = {};

  int rowc = tid >> 3, slot = tid & 7;
  int kswz = (slot ^ (rowc & 7)) << 4;
  int fcol = (slot ^ (rowc & 7)) << 3;

  auto stageA = [&](int buf, int kt) {
#pragma unroll
    for (int c = 0; c < 4; ++c) {
      const char* ga = (const char*)A + (size_t)(m0 + c * 32 + rowc) * 1024 + kt * 128 + kswz;
      gl16(ga, (char*)&As[buf][0] + c * 4096 + (wid << 10));
    }
  };
  float4 lvb[4];
  auto LOADW = [&](int kt) {
#pragma unroll
    for (int c = 0; c < 2; ++c) {
      const float* g = Wf + (size_t)(n0 + c * 32 + rowc) * 512 + kt * 64 + fcol;
      lvb[c * 2] = *(const float4*)g;
      lvb[c * 2 + 1] = *(const float4*)(g + 4);
    }
  };
  auto WRITEW = [&](int buf) {
#pragma unroll
    for (int c = 0; c < 2; ++c)
      *(uint4*)((char*)&Bs[buf][0] + c * 4096 + rowc * 128 + slot * 16) =
          cvt8(lvb[c * 2], lvb[c * 2 + 1]);
  };

  stageA(0, 0);
  LOADW(0);
  WRITEW(0);

  int wm = wid >> 1, wn = wid & 1;
  int fr = lane & 15, fg = lane >> 4;

#pragma unroll 1
  for (int kt = 0; kt < 8; ++kt) {
    __syncthreads();
    if (kt < 7) { stageA((kt + 1) & 1, kt + 1); LOADW(kt + 1); }
    int buf = kt & 1;
#pragma unroll
    for (int ks = 0; ks < 2; ++ks) {
      bf16x8 a[4], b[2];
#pragma unroll
      for (int mi = 0; mi < 4; ++mi)
        a[mi] = *(const bf16x8*)&As[buf][swzi(wm * 64 + mi * 16 + fr, ks * 64 + fg * 16)];
#pragma unroll
      for (int ni = 0; ni < 2; ++ni)
        b[ni] = *(const bf16x8*)&Bs[buf][swzi(wn * 32 + ni * 16 + fr, ks * 64 + fg * 16)];
#pragma unroll
      for (int mi = 0; mi < 4; ++mi)
#pragma unroll
        for (int ni = 0; ni < 2; ++ni)
          acc[mi][ni] = __builtin_amdgcn_mfma_f32_16x16x32_bf16(a[mi], b[ni], acc[mi][ni], 0, 0, 0);
    }
    if (kt < 7) WRITEW((kt + 1) & 1);
  }

#pragma unroll
  for (int mi = 0; mi < 4; ++mi)
#pragma unroll
    for (int ni = 0; ni < 2; ++ni)
#pragma unroll
      for (int i = 0; i < 4; ++i) {
        int gm = m0 + wm * 64 + mi * 16 + fg * 4 + i;
        int gn = n0 + wn * 32 + ni * 16 + fr;
        outp[(size_t)gm * E_ + gn] = acc[mi][ni][i] + bias[gn];
      }
}

// ---------------------------------------------------------------- flash attention
// Q,K are logistic-map outputs => all scores >= 0, s_log2 <= ~11, exp2(s) <= ~2k,
// l <= ~4e6: NO max subtraction needed (scale cancels in O/l). P = exp2(s) directly.
// T15-style pair pipeline: QK_a -> (QK_b || SM_a) -> (PV_a || SM_b) -> PV_b.
template <int CBa, int CBb>
__device__ __forceinline__ void tile_pair(
    char* sm, int koff0, int koff1, const int (&voff)[4],
    const bf16x8 (&qa)[2][2], f32x4 (&acco)[2][4], float (&lst)[2]) {
  union PU { unsigned u[2]; bf16x4 v; };

  // ---- K_a fragments + QK_a
  bf16x8 ka[4][2];
#pragma unroll
  for (int ni = 0; ni < 4; ++ni) {
    ka[ni][0] = *(const bf16x8*)(sm + CBa + ni * 2048 + koff0);
    ka[ni][1] = *(const bf16x8*)(sm + CBa + ni * 2048 + koff1);
  }
  f32x4 sta[4][2] = {};
  __builtin_amdgcn_s_setprio(1);
#pragma unroll
  for (int ni = 0; ni < 4; ++ni)
#pragma unroll
    for (int mi = 0; mi < 2; ++mi) {
      sta[ni][mi] = __builtin_amdgcn_mfma_f32_16x16x32_bf16(ka[ni][0], qa[mi][0], sta[ni][mi], 0, 0, 0);
      sta[ni][mi] = __builtin_amdgcn_mfma_f32_16x16x32_bf16(ka[ni][1], qa[mi][1], sta[ni][mi], 0, 0, 0);
    }
  __builtin_amdgcn_s_setprio(0);

  // ---- K_b fragments + QK_b (MFMA pipe) ...
  bf16x8 kb[4][2];
#pragma unroll
  for (int ni = 0; ni < 4; ++ni) {
    kb[ni][0] = *(const bf16x8*)(sm + CBb + ni * 2048 + koff0);
    kb[ni][1] = *(const bf16x8*)(sm + CBb + ni * 2048 + koff1);
  }
  f32x4 stb[4][2] = {};
  __builtin_amdgcn_s_setprio(1);
#pragma unroll
  for (int ni = 0; ni < 4; ++ni)
#pragma unroll
    for (int mi = 0; mi < 2; ++mi) {
      stb[ni][mi] = __builtin_amdgcn_mfma_f32_16x16x32_bf16(kb[ni][0], qa[mi][0], stb[ni][mi], 0, 0, 0);
      stb[ni][mi] = __builtin_amdgcn_mfma_f32_16x16x32_bf16(kb[ni][1], qa[mi][1], stb[ni][mi], 0, 0, 0);
    }
  __builtin_amdgcn_s_setprio(0);

  // ---- ... SM_a (VALU) overlaps QK_b's pipe time
  bf16x4 pfa[2][4];
#pragma unroll
  for (int mi = 0; mi < 2; ++mi) {
    float sum = 0.f;
#pragma unroll
    for (int ni = 0; ni < 4; ++ni) {
      float p0 = __builtin_amdgcn_exp2f(sta[ni][mi][0]);
      float p1 = __builtin_amdgcn_exp2f(sta[ni][mi][1]);
      float p2 = __builtin_amdgcn_exp2f(sta[ni][mi][2]);
      float p3 = __builtin_amdgcn_exp2f(sta[ni][mi][3]);
      sum += (p0 + p1) + (p2 + p3);
      PU pu;
      asm("v_cvt_pk_bf16_f32 %0, %1, %2" : "=v"(pu.u[0]) : "v"(p0), "v"(p1));
      asm("v_cvt_pk_bf16_f32 %0, %1, %2" : "=v"(pu.u[1]) : "v"(p2), "v"(p3));
      pfa[mi][ni] = pu.v;
    }
    sum += __shfl_xor(sum, 16);
    sum += __shfl_xor(sum, 32);
    lst[mi] += sum;
  }

  // ---- PV_a (MFMA pipe) ...
  __builtin_amdgcn_s_setprio(1);
#pragma unroll
  for (int nd = 0; nd < 4; ++nd)
#pragma unroll
    for (int ni = 0; ni < 4; ++ni) {
      bf16x4 vf = *(const bf16x4*)(sm + CBa + nd * 2048 + voff[ni]);
#pragma unroll
      for (int mi = 0; mi < 2; ++mi)
        acco[mi][nd] = mfma16x16x16(vf, pfa[mi][ni], acco[mi][nd]);
    }
  __builtin_amdgcn_s_setprio(0);

  // ---- ... SM_b (VALU) overlaps PV_a's pipe time
  bf16x4 pfb[2][4];
#pragma unroll
  for (int mi = 0; mi < 2; ++mi) {
    float sum = 0.f;
#pragma unroll
    for (int ni = 0; ni < 4; ++ni) {
      float p0 = __builtin_amdgcn_exp2f(stb[ni][mi][0]);
      float p1 = __builtin_amdgcn_exp2f(stb[ni][mi][1]);
      float p2 = __builtin_amdgcn_exp2f(stb[ni][mi][2]);
      float p3 = __builtin_amdgcn_exp2f(stb[ni][mi][3]);
      sum += (p0 + p1) + (p2 + p3);
      PU pu;
      asm("v_cvt_pk_bf16_f32 %0, %1, %2" : "=v"(pu.u[0]) : "v"(p0), "v"(p1));
      asm("v_cvt_pk_bf16_f32 %0, %1, %2" : "=v"(pu.u[1]) : "v"(p2), "v"(p3));
      pfb[mi][ni] = pu.v;
    }
    sum += __shfl_xor(sum, 16);
    sum += __shfl_xor(sum, 32);
    lst[mi] += sum;
  }

  // ---- PV_b
  __builtin_amdgcn_s_setprio(1);
#pragma unroll
  for (int nd = 0; nd < 4; ++nd)
#pragma unroll
    for (int ni = 0; ni < 4; ++ni) {
      bf16x4 vf = *(const bf16x4*)(sm + CBb + nd * 2048 + voff[ni]);
#pragma unroll
      for (int mi = 0; mi < 2; ++mi)
        acco[mi][nd] = mfma16x16x16(vf, pfb[mi][ni], acco[mi][nd]);
    }
  __builtin_amdgcn_s_setprio(0);
}

// grid: 512 blocks = 32 (b,h) * 16 Q-tiles of 128 rows. 4 waves * 32 rows.
// 4 KV buffers of 16KB (K 8KB + V 8KB); Q staged in buf3 then moved to regs.
// One barrier per 2 KV tiles; stages have 2 full tile-computes to land.
// XCD-bijective swizzle (512%8==0): 64 consecutive wgid (4 bh) per XCD L2.
__global__ __launch_bounds__(256) void attn_flash(
    const unsigned short* __restrict__ qp,   // [B,H,T,D], pre-scaled by 0.125*log2e
    const unsigned short* __restrict__ kp,   // [B,H,S,D]
    const unsigned short* __restrict__ vtp,  // [B,H,D,S]
    unsigned short* __restrict__ attno) {    // [B*T, E]
  __shared__ __align__(16) char smem[65536];

  int tid = threadIdx.x, lane = tid & 63, wid = tid >> 6;
  int wgid = ((blockIdx.x & 7) << 6) + (blockIdx.x >> 3);  // 512 blocks, 8 XCDs
  int tt = wgid & 15, bh = wgid >> 4;
  const char* qh = (const char*)qp + ((size_t)bh * T_ + tt * 128) * 128;
  const char* kh = (const char*)kp + (size_t)bh * S_ * 128;
  const char* vh = (const char*)vtp + (size_t)bh * D_ * S_ * 2;

  int rowc = tid >> 3;
  int kswz = ((tid & 7) ^ (rowc & 7)) << 4;

#define STAGE_K(SB, IT) { \
    gl16(kh + (size_t)((IT) * 64 + rowc) * 128 + kswz, smem + (SB) + (wid << 10)); \
    gl16(kh + (size_t)((IT) * 64 + 32 + rowc) * 128 + kswz, smem + (SB) + 4096 + (wid << 10)); }
#define STAGE_V(SB, IT) { \
    gl16(vh + (size_t)rowc * 4096 + (IT) * 128 + kswz, smem + (SB) + 8192 + (wid << 10)); \
    gl16(vh + (size_t)(32 + rowc) * 4096 + (IT) * 128 + kswz, smem + (SB) + 12288 + (wid << 10)); }

  // prologue: KV0 -> b0, KV1 -> b1, Q -> b3
  STAGE_K(0, 0) STAGE_V(0, 0) STAGE_K(16384, 1) STAGE_V(16384, 1)
#pragma unroll
  for (int c = 0; c < 4; ++c)
    gl16(qh + (size_t)(c * 32 + rowc) * 128 + kswz, smem + 49152 + c * 4096 + (wid << 10));

  int fr = lane & 15, fg = (lane >> 4) & 3;
  int qrb = wid * 32;
  // hoisted per-lane swizzled LDS byte offsets (col bytes: ks*64 + fg*16, XOR (fr&7)<<4)
  int koff0 = fr * 128 + ((fg * 16) ^ ((fr & 7) << 4));
  int koff1 = fr * 128 + ((64 + fg * 16) ^ ((fr & 7) << 4));
  int voff[4];
#pragma unroll
  for (int ni = 0; ni < 4; ++ni)
    voff[ni] = 8192 + fr * 128 + ((ni * 32 + fg * 8) ^ ((fr & 7) << 4));

  __syncthreads();   // Q, KV0, KV1 landed (vmcnt drained)

  // Q fragments -> registers; buf3 then becomes a KV buffer
  bf16x8 qa[2][2];
#pragma unroll
  for (int mi = 0; mi < 2; ++mi) {
    qa[mi][0] = *(const bf16x8*)(smem + 49152 + (qrb + mi * 16) * 128 + koff0);
    qa[mi][1] = *(const bf16x8*)(smem + 49152 + (qrb + mi * 16) * 128 + koff1);
  }
  __syncthreads();   // ALL waves' Q reads done before b3 is overwritten below

  f32x4 acco[2][4] = {};
  float lst[2] = {0.f, 0.f};

  // pair 0: stage KV2->b2, KV3->b3; compute tiles 0,1
  STAGE_K(32768, 2) STAGE_V(32768, 2) STAGE_K(49152, 3) STAGE_V(49152, 3)
  tile_pair<0, 16384>(smem, koff0, koff1, voff, qa, acco, lst);

#pragma unroll 1
  for (int pp = 1; pp <= 7; ++pp) {
    int ta = pp * 4;
    __syncthreads();                                  // b2,b3 landed; b0,b1 reads done
    STAGE_K(0, ta) STAGE_V(0, ta) STAGE_K(16384, ta + 1) STAGE_V(16384, ta + 1)
    tile_pair<32768, 49152>(smem, koff0, koff1, voff, qa, acco, lst);
    __syncthreads();                                  // b0,b1 landed; b2,b3 reads done
    STAGE_K(32768, ta + 2) STAGE_V(32768, ta + 2) STAGE_K(49152, ta + 3) STAGE_V(49152, ta + 3)
    tile_pair<0, 16384>(smem, koff0, koff1, voff, qa, acco, lst);
  }
  __syncthreads();                                    // tiles 30,31 landed
  tile_pair<32768, 49152>(smem, koff0, koff1, voff, qa, acco, lst);

  // ---- epilogue: O^T lane holds q=16mi+fr, d=16nd+4fg+reg; divide by l, 8B stores
  int b = bh >> 3, h = bh & 7;
#pragma unroll
  for (int mi = 0; mi < 2; ++mi) {
    float rl = 1.0f / lst[mi];
    int t = tt * 128 + qrb + mi * 16 + fr;
    unsigned short* rowp = attno + (size_t)(b * T_ + t) * E_ + h * 64;
#pragma unroll
    for (int nd = 0; nd < 4; ++nd) {
      ushort4 o;
      o.x = f2bf(acco[mi][nd][0] * rl);
      o.y = f2bf(acco[mi][nd][1] * rl);
      o.z = f2bf(acco[mi][nd][2] * rl);
      o.w = f2bf(acco[mi][nd][3] * rl);
      *(ushort4*)(rowp + nd * 16 + fg * 4) = o;
    }
  }
#undef STAGE_K
#undef STAGE_V
}

// ---------------------------------------------------------------- launch
extern "C" void kernel_launch(void* const* d_in, const int* in_sizes, int n_in,
                              void* d_out, int out_size, void* d_ws, size_t ws_size,
                              hipStream_t stream) {
  const float* query = (const float*)d_in[0];
  const float* key_  = (const float*)d_in[1];
  const float* value = (const float*)d_in[2];
  const float* Wq    = (const float*)d_in[3];
  const float* bq    = (const float*)d_in[4];
  const float* Wk    = (const float*)d_in[5];
  const float* bk    = (const float*)d_in[6];
  const float* Wv    = (const float*)d_in[7];
  const float* bv    = (const float*)d_in[8];
  const float* Wo    = (const float*)d_in[9];
  const float* bo    = (const float*)d_in[10];
  const float* r     = (const float*)d_in[11];

  char* ws = (char*)d_ws;
  unsigned short* qp    = (unsigned short*)(ws + 27262976);   //  8 MiB  [B,H,T,D]
  unsigned short* kp    = (unsigned short*)(ws + 35651584);   //  8 MiB  [B,H,S,D]
  unsigned short* vtp   = (unsigned short*)(ws + 44040192);   //  8 MiB  [B,H,D,S]
  unsigned short* attno = (unsigned short*)(ws + 52428800);   //  8 MiB  [B*T, E]

  const float SCLQ = 0.125f * 1.44269504089f;  // fold 1/sqrt(D) * log2(e) into Q

  // Fused fp32->bf16 staging inside the GEMMs — no separate convert pass.
  gemm_proj<<<1536, 256, 0, stream>>>(query, Wq, bq, qp,
                                      key_, Wk, bk, kp,
                                      Wv, value, bv, vtp, r, SCLQ);

  attn_flash<<<512, 256, 0, stream>>>(qp, kp, vtp, attno);

  // out = attno Wo^T + bo  (fp32)
  gemm_out<<<512, 256, 0, stream>>>(attno, Wo, bo, (float*)d_out);
}

// Round 19
// 112.410 us; speedup vs baseline: 1.0502x; 1.0502x over previous
//
#include <hip/hip_runtime.h>
#include <stdint.h>

#define B_ 4
#define T_ 2048
#define S_ 2048
#define E_ 512
#define H_ 8
#define D_ 64

using bf16x8 = __attribute__((ext_vector_type(8))) short;
using bf16x4 = __attribute__((ext_vector_type(4))) short;
using f32x4  = __attribute__((ext_vector_type(4))) float;

__device__ __forceinline__ unsigned short f2bf(float f) {
  unsigned u = __float_as_uint(f);
  u += 0x7fffu + ((u >> 16) & 1u);          // round-to-nearest-even
  return (unsigned short)(u >> 16);
}

__device__ __forceinline__ float sigmoidf_(float x) {
  return 1.0f / (1.0f + __expf(-x));
}

// 8 fp32 -> 8 bf16 packed in a uint4, via HW packed converts
__device__ __forceinline__ uint4 cvt8(float4 a, float4 b) {
  uint4 r;
  asm("v_cvt_pk_bf16_f32 %0, %1, %2" : "=v"(r.x) : "v"(a.x), "v"(a.y));
  asm("v_cvt_pk_bf16_f32 %0, %1, %2" : "=v"(r.y) : "v"(a.z), "v"(a.w));
  asm("v_cvt_pk_bf16_f32 %0, %1, %2" : "=v"(r.z) : "v"(b.x), "v"(b.y));
  asm("v_cvt_pk_bf16_f32 %0, %1, %2" : "=v"(r.w) : "v"(b.z), "v"(b.w));
  return r;
}

// legacy K=16 bf16 MFMA: A/B = 4 bf16 (2 VGPR), layout row=lane&15, k=(lane>>4)*4+e
__device__ __forceinline__ f32x4 mfma16x16x16(bf16x4 a, bf16x4 b, f32x4 c) {
#if __has_builtin(__builtin_amdgcn_mfma_f32_16x16x16bf16_1k)
  return __builtin_amdgcn_mfma_f32_16x16x16bf16_1k(a, b, c, 0, 0, 0);
#else
  asm("v_mfma_f32_16x16x16_bf16 %0, %1, %2, %0" : "+v"(c) : "v"(a), "v"(b));
  return c;
#endif
}

// async global->LDS, 16B per lane. LDS dest = wave-uniform base + lane*16.
__device__ __forceinline__ void gl16(const void* g, void* l) {
  __builtin_amdgcn_global_load_lds(
      (const __attribute__((address_space(1))) unsigned*)g,
      (__attribute__((address_space(3))) unsigned*)l,
      16, 0, 0);
}

// T2 swizzle for [R][64 bf16] (128B-row) LDS tiles:
// physical byte-in-row = logical byte-in-row ^ ((row&7)<<4).
__device__ __forceinline__ int swzi(int row, int ebyte) {
  return row * 64 + ((ebyte ^ ((row & 7) << 4)) >> 1);
}

// ---------------------------------------------------------------- merged projection GEMMs
// One launch, 1536 blocks (512/job, 128x64 tiles). ALL operands are raw fp32
// inputs: staging = global fp32 -> v_cvt_pk_bf16 -> swizzled ds_write (fuses
// the former cvt pass into the GEMM; T14 split: loads issued before the MFMA
// block, writes after, so HBM latency hides under compute like gl16 did).
// NOTE (R18 post-mortem): 1-deep staging with 72 VGPR / 27% occupancy beats a
// 2-deep register pipeline at 112 VGPR / 19% — waves > in-wave pipelining here.
// job 0: C=logistic(query Wq^T+bq)*sclq -> [B,H,T,D]
// job 1: C=logistic(key  Wk^T+bk)      -> [B,H,S,D]
// job 2: C=(Wv value^T+bv)             -> [B,H,D,S]   (A=Wv, W=value)
__global__ __launch_bounds__(256) void gemm_proj(
    const float* __restrict__ Aq, const float* __restrict__ Wqf,
    const float* __restrict__ bqp, unsigned short* __restrict__ oq,
    const float* __restrict__ Ak, const float* __restrict__ Wkf,
    const float* __restrict__ bkp, unsigned short* __restrict__ ok,
    const float* __restrict__ Wvf, const float* __restrict__ Av,
    const float* __restrict__ bvp, unsigned short* __restrict__ ov,
    const float* __restrict__ rptr, float sclq) {
  __shared__ unsigned short As[2][128 * 64];   // 32 KB
  __shared__ unsigned short Bs[2][64 * 64];    // 16 KB

  int job = blockIdx.x >> 9;                     // 0,1,2 (uniform per block)
  int x = blockIdx.x & 511;
  int bid = ((x & 7) << 6) + (x >> 3);           // XCD-bijective within job
  const float* A = (job == 0) ? Aq : (job == 1) ? Ak : Wvf;
  const float* W = (job == 0) ? Wqf : (job == 1) ? Wkf : Av;
  const float* bias = (job == 0) ? bqp : (job == 1) ? bkp : bvp;
  unsigned short* outp = (job == 0) ? oq : (job == 1) ? ok : ov;

  int bm, bn;
  if (job == 2) { bm = bid >> 7; bn = bid & 127; }   // M=512 (e), N=8192 (b*s)
  else          { bm = bid >> 3; bn = bid & 7; }     // M=8192, N=512
  int m0 = bm * 128, n0 = bn * 64;

  f32x4 acc[4][2] = {};

  int tid = threadIdx.x;
  int lane = tid & 63, wid = tid >> 6;
  int rowc = tid >> 3, slot = tid & 7;
  int fcol = (slot ^ (rowc & 7)) << 3;            // pre-swizzled fp32 col (8 floats)

  float4 lva[8], lvb[4];                          // in-flight fp32 (static idx)
  auto LOAD = [&](int kt) {
#pragma unroll
    for (int c = 0; c < 4; ++c) {
      const float* g = A + (size_t)(m0 + c * 32 + rowc) * 512 + kt * 64 + fcol;
      lva[c * 2] = *(const float4*)g;
      lva[c * 2 + 1] = *(const float4*)(g + 4);
    }
#pragma unroll
    for (int c = 0; c < 2; ++c) {
      const float* g = W + (size_t)(n0 + c * 32 + rowc) * 512 + kt * 64 + fcol;
      lvb[c * 2] = *(const float4*)g;
      lvb[c * 2 + 1] = *(const float4*)(g + 4);
    }
  };
  auto WRITE = [&](int buf) {
#pragma unroll
    for (int c = 0; c < 4; ++c)
      *(uint4*)((char*)&As[buf][0] + c * 4096 + rowc * 128 + slot * 16) =
          cvt8(lva[c * 2], lva[c * 2 + 1]);
#pragma unroll
    for (int c = 0; c < 2; ++c)
      *(uint4*)((char*)&Bs[buf][0] + c * 4096 + rowc * 128 + slot * 16) =
          cvt8(lvb[c * 2], lvb[c * 2 + 1]);
  };

  LOAD(0);
  WRITE(0);

  int wm = wid >> 1, wn = wid & 1;       // 2x2 waves; each wave 64(M) x 32(N)
  int fr = lane & 15, fg = lane >> 4;

#pragma unroll 1
  for (int kt = 0; kt < 8; ++kt) {
    __syncthreads();                     // buf=kt&1 writes visible to all waves
    if (kt < 7) LOAD(kt + 1);            // issue next-tile loads (in flight over MFMA)
    int buf = kt & 1;
#pragma unroll
    for (int ks = 0; ks < 2; ++ks) {
      bf16x8 a[4], b[2];
#pragma unroll
      for (int mi = 0; mi < 4; ++mi)
        a[mi] = *(const bf16x8*)&As[buf][swzi(wm * 64 + mi * 16 + fr, ks * 64 + fg * 16)];
#pragma unroll
      for (int ni = 0; ni < 2; ++ni)
        b[ni] = *(const bf16x8*)&Bs[buf][swzi(wn * 32 + ni * 16 + fr, ks * 64 + fg * 16)];
#pragma unroll
      for (int mi = 0; mi < 4; ++mi)
#pragma unroll
        for (int ni = 0; ni < 2; ++ni)
          acc[mi][ni] = __builtin_amdgcn_mfma_f32_16x16x32_bf16(a[mi], b[ni], acc[mi][ni], 0, 0, 0);
    }
    if (kt < 7) WRITE((kt + 1) & 1);     // cvt + ds_write after compute (T14 split)
  }

  float rs = 4.0f * sigmoidf_(rptr[0]) * ((job == 0) ? sclq : 1.0f);

#pragma unroll
  for (int mi = 0; mi < 4; ++mi) {
#pragma unroll
    for (int ni = 0; ni < 2; ++ni) {
#pragma unroll
      for (int i = 0; i < 4; ++i) {
        int gm = m0 + wm * 64 + mi * 16 + fg * 4 + i;   // C row
        int gn = n0 + wn * 32 + ni * 16 + fr;           // C col
        float v = acc[mi][ni][i];
        if (job < 2) {
          v += bias[gn];
          float xn = sigmoidf_(v);
          float val = rs * xn * (1.0f - xn);
          int b = gm >> 11, t = gm & 2047, h = gn >> 6, d = gn & 63;
          outp[((size_t)(b * H_ + h) * T_ + t) * D_ + d] = f2bf(val);
        } else {
          v += bias[gm];                                // bias indexed by e = row
          int h = gm >> 6, d = gm & 63, b = gn >> 11, s = gn & 2047;
          outp[((size_t)(b * H_ + h) * D_ + d) * S_ + s] = f2bf(v);
        }
      }
    }
  }
}

// ---------------------------------------------------------------- GEMM (output proj)
// C = attno(bf16, gl16-staged) x Wo(fp32, reg-staged+cvt)^T + bo, fp32 out.
__global__ __launch_bounds__(256) void gemm_out(
    const unsigned short* __restrict__ A,
    const float* __restrict__ Wf,
    const float* __restrict__ bias,
    float* __restrict__ outp) {
  __shared__ unsigned short As[2][128 * 64];   // 32 KB
  __shared__ unsigned short Bs[2][64 * 64];    // 16 KB

  int bid = ((blockIdx.x & 7) << 6) + (blockIdx.x >> 3);  // 512 blocks, 8 XCDs
  int tid = threadIdx.x;
  int lane = tid & 63, wid = tid >> 6;
  int bm = bid >> 3, bn = bid & 7;
  int m0 = bm * 128, n0 = bn * 64;

  f32x4 acc[4][2] = {};

  int rowc = tid >> 3, slot = tid & 7;
  int kswz = (slot ^ (rowc & 7)) << 4;
  int fcol = (slot ^ (rowc & 7)) << 3;

  auto stageA = [&](int buf, int kt) {
#pragma unroll
    for (int c = 0; c < 4; ++c) {
      const char* ga = (const char*)A + (size_t)(m0 + c * 32 + rowc) * 1024 + kt * 128 + kswz;
      gl16(ga, (char*)&As[buf][0] + c * 4096 + (wid << 10));
    }
  };
  float4 lvb[4];
  auto LOADW = [&](int kt) {
#pragma unroll
    for (int c = 0; c < 2; ++c) {
      const float* g = Wf + (size_t)(n0 + c * 32 + rowc) * 512 + kt * 64 + fcol;
      lvb[c * 2] = *(const float4*)g;
      lvb[c * 2 + 1] = *(const float4*)(g + 4);
    }
  };
  auto WRITEW = [&](int buf) {
#pragma unroll
    for (int c = 0; c < 2; ++c)
      *(uint4*)((char*)&Bs[buf][0] + c * 4096 + rowc * 128 + slot * 16) =
          cvt8(lvb[c * 2], lvb[c * 2 + 1]);
  };

  stageA(0, 0);
  LOADW(0);
  WRITEW(0);

  int wm = wid >> 1, wn = wid & 1;
  int fr = lane & 15, fg = lane >> 4;

#pragma unroll 1
  for (int kt = 0; kt < 8; ++kt) {
    __syncthreads();
    if (kt < 7) { stageA((kt + 1) & 1, kt + 1); LOADW(kt + 1); }
    int buf = kt & 1;
#pragma unroll
    for (int ks = 0; ks < 2; ++ks) {
      bf16x8 a[4], b[2];
#pragma unroll
      for (int mi = 0; mi < 4; ++mi)
        a[mi] = *(const bf16x8*)&As[buf][swzi(wm * 64 + mi * 16 + fr, ks * 64 + fg * 16)];
#pragma unroll
      for (int ni = 0; ni < 2; ++ni)
        b[ni] = *(const bf16x8*)&Bs[buf][swzi(wn * 32 + ni * 16 + fr, ks * 64 + fg * 16)];
#pragma unroll
      for (int mi = 0; mi < 4; ++mi)
#pragma unroll
        for (int ni = 0; ni < 2; ++ni)
          acc[mi][ni] = __builtin_amdgcn_mfma_f32_16x16x32_bf16(a[mi], b[ni], acc[mi][ni], 0, 0, 0);
    }
    if (kt < 7) WRITEW((kt + 1) & 1);
  }

#pragma unroll
  for (int mi = 0; mi < 4; ++mi)
#pragma unroll
    for (int ni = 0; ni < 2; ++ni)
#pragma unroll
      for (int i = 0; i < 4; ++i) {
        int gm = m0 + wm * 64 + mi * 16 + fg * 4 + i;
        int gn = n0 + wn * 32 + ni * 16 + fr;
        outp[(size_t)gm * E_ + gn] = acc[mi][ni][i] + bias[gn];
      }
}

// ---------------------------------------------------------------- flash attention
// Q,K are logistic-map outputs => all scores >= 0, s_log2 <= ~11, exp2(s) <= ~2k,
// l <= ~4e6: NO max subtraction needed (scale cancels in O/l). P = exp2(s) directly.
// T15-style pair pipeline: QK_a -> (QK_b || SM_a) -> (PV_a || SM_b) -> PV_b.
template <int CBa, int CBb>
__device__ __forceinline__ void tile_pair(
    char* sm, int koff0, int koff1, const int (&voff)[4],
    const bf16x8 (&qa)[2][2], f32x4 (&acco)[2][4], float (&lst)[2]) {
  union PU { unsigned u[2]; bf16x4 v; };

  // ---- K_a fragments + QK_a
  bf16x8 ka[4][2];
#pragma unroll
  for (int ni = 0; ni < 4; ++ni) {
    ka[ni][0] = *(const bf16x8*)(sm + CBa + ni * 2048 + koff0);
    ka[ni][1] = *(const bf16x8*)(sm + CBa + ni * 2048 + koff1);
  }
  f32x4 sta[4][2] = {};
  __builtin_amdgcn_s_setprio(1);
#pragma unroll
  for (int ni = 0; ni < 4; ++ni)
#pragma unroll
    for (int mi = 0; mi < 2; ++mi) {
      sta[ni][mi] = __builtin_amdgcn_mfma_f32_16x16x32_bf16(ka[ni][0], qa[mi][0], sta[ni][mi], 0, 0, 0);
      sta[ni][mi] = __builtin_amdgcn_mfma_f32_16x16x32_bf16(ka[ni][1], qa[mi][1], sta[ni][mi], 0, 0, 0);
    }
  __builtin_amdgcn_s_setprio(0);

  // ---- K_b fragments + QK_b (MFMA pipe) ...
  bf16x8 kb[4][2];
#pragma unroll
  for (int ni = 0; ni < 4; ++ni) {
    kb[ni][0] = *(const bf16x8*)(sm + CBb + ni * 2048 + koff0);
    kb[ni][1] = *(const bf16x8*)(sm + CBb + ni * 2048 + koff1);
  }
  f32x4 stb[4][2] = {};
  __builtin_amdgcn_s_setprio(1);
#pragma unroll
  for (int ni = 0; ni < 4; ++ni)
#pragma unroll
    for (int mi = 0; mi < 2; ++mi) {
      stb[ni][mi] = __builtin_amdgcn_mfma_f32_16x16x32_bf16(kb[ni][0], qa[mi][0], stb[ni][mi], 0, 0, 0);
      stb[ni][mi] = __builtin_amdgcn_mfma_f32_16x16x32_bf16(kb[ni][1], qa[mi][1], stb[ni][mi], 0, 0, 0);
    }
  __builtin_amdgcn_s_setprio(0);

  // ---- ... SM_a (VALU) overlaps QK_b's pipe time
  bf16x4 pfa[2][4];
#pragma unroll
  for (int mi = 0; mi < 2; ++mi) {
    float sum = 0.f;
#pragma unroll
    for (int ni = 0; ni < 4; ++ni) {
      float p0 = __builtin_amdgcn_exp2f(sta[ni][mi][0]);
      float p1 = __builtin_amdgcn_exp2f(sta[ni][mi][1]);
      float p2 = __builtin_amdgcn_exp2f(sta[ni][mi][2]);
      float p3 = __builtin_amdgcn_exp2f(sta[ni][mi][3]);
      sum += (p0 + p1) + (p2 + p3);
      PU pu;
      asm("v_cvt_pk_bf16_f32 %0, %1, %2" : "=v"(pu.u[0]) : "v"(p0), "v"(p1));
      asm("v_cvt_pk_bf16_f32 %0, %1, %2" : "=v"(pu.u[1]) : "v"(p2), "v"(p3));
      pfa[mi][ni] = pu.v;
    }
    sum += __shfl_xor(sum, 16);
    sum += __shfl_xor(sum, 32);
    lst[mi] += sum;
  }

  // ---- PV_a (MFMA pipe) ...
  __builtin_amdgcn_s_setprio(1);
#pragma unroll
  for (int nd = 0; nd < 4; ++nd)
#pragma unroll
    for (int ni = 0; ni < 4; ++ni) {
      bf16x4 vf = *(const bf16x4*)(sm + CBa + nd * 2048 + voff[ni]);
#pragma unroll
      for (int mi = 0; mi < 2; ++mi)
        acco[mi][nd] = mfma16x16x16(vf, pfa[mi][ni], acco[mi][nd]);
    }
  __builtin_amdgcn_s_setprio(0);

  // ---- ... SM_b (VALU) overlaps PV_a's pipe time
  bf16x4 pfb[2][4];
#pragma unroll
  for (int mi = 0; mi < 2; ++mi) {
    float sum = 0.f;
#pragma unroll
    for (int ni = 0; ni < 4; ++ni) {
      float p0 = __builtin_amdgcn_exp2f(stb[ni][mi][0]);
      float p1 = __builtin_amdgcn_exp2f(stb[ni][mi][1]);
      float p2 = __builtin_amdgcn_exp2f(stb[ni][mi][2]);
      float p3 = __builtin_amdgcn_exp2f(stb[ni][mi][3]);
      sum += (p0 + p1) + (p2 + p3);
      PU pu;
      asm("v_cvt_pk_bf16_f32 %0, %1, %2" : "=v"(pu.u[0]) : "v"(p0), "v"(p1));
      asm("v_cvt_pk_bf16_f32 %0, %1, %2" : "=v"(pu.u[1]) : "v"(p2), "v"(p3));
      pfb[mi][ni] = pu.v;
    }
    sum += __shfl_xor(sum, 16);
    sum += __shfl_xor(sum, 32);
    lst[mi] += sum;
  }

  // ---- PV_b
  __builtin_amdgcn_s_setprio(1);
#pragma unroll
  for (int nd = 0; nd < 4; ++nd)
#pragma unroll
    for (int ni = 0; ni < 4; ++ni) {
      bf16x4 vf = *(const bf16x4*)(sm + CBb + nd * 2048 + voff[ni]);
#pragma unroll
      for (int mi = 0; mi < 2; ++mi)
        acco[mi][nd] = mfma16x16x16(vf, pfb[mi][ni], acco[mi][nd]);
    }
  __builtin_amdgcn_s_setprio(0);
}

// grid: 512 blocks = 32 (b,h) * 16 Q-tiles of 128 rows. 4 waves * 32 rows.
// 4 KV buffers of 16KB (K 8KB + V 8KB); Q staged in buf3 then moved to regs.
// One barrier per 2 KV tiles; stages have 2 full tile-computes to land.
// XCD-bijective swizzle (512%8==0): 64 consecutive wgid (4 bh) per XCD L2.
__global__ __launch_bounds__(256) void attn_flash(
    const unsigned short* __restrict__ qp,   // [B,H,T,D], pre-scaled by 0.125*log2e
    const unsigned short* __restrict__ kp,   // [B,H,S,D]
    const unsigned short* __restrict__ vtp,  // [B,H,D,S]
    unsigned short* __restrict__ attno) {    // [B*T, E]
  __shared__ __align__(16) char smem[65536];

  int tid = threadIdx.x, lane = tid & 63, wid = tid >> 6;
  int wgid = ((blockIdx.x & 7) << 6) + (blockIdx.x >> 3);  // 512 blocks, 8 XCDs
  int tt = wgid & 15, bh = wgid >> 4;
  const char* qh = (const char*)qp + ((size_t)bh * T_ + tt * 128) * 128;
  const char* kh = (const char*)kp + (size_t)bh * S_ * 128;
  const char* vh = (const char*)vtp + (size_t)bh * D_ * S_ * 2;

  int rowc = tid >> 3;
  int kswz = ((tid & 7) ^ (rowc & 7)) << 4;

#define STAGE_K(SB, IT) { \
    gl16(kh + (size_t)((IT) * 64 + rowc) * 128 + kswz, smem + (SB) + (wid << 10)); \
    gl16(kh + (size_t)((IT) * 64 + 32 + rowc) * 128 + kswz, smem + (SB) + 4096 + (wid << 10)); }
#define STAGE_V(SB, IT) { \
    gl16(vh + (size_t)rowc * 4096 + (IT) * 128 + kswz, smem + (SB) + 8192 + (wid << 10)); \
    gl16(vh + (size_t)(32 + rowc) * 4096 + (IT) * 128 + kswz, smem + (SB) + 12288 + (wid << 10)); }

  // prologue: KV0 -> b0, KV1 -> b1, Q -> b3
  STAGE_K(0, 0) STAGE_V(0, 0) STAGE_K(16384, 1) STAGE_V(16384, 1)
#pragma unroll
  for (int c = 0; c < 4; ++c)
    gl16(qh + (size_t)(c * 32 + rowc) * 128 + kswz, smem + 49152 + c * 4096 + (wid << 10));

  int fr = lane & 15, fg = (lane >> 4) & 3;
  int qrb = wid * 32;
  // hoisted per-lane swizzled LDS byte offsets (col bytes: ks*64 + fg*16, XOR (fr&7)<<4)
  int koff0 = fr * 128 + ((fg * 16) ^ ((fr & 7) << 4));
  int koff1 = fr * 128 + ((64 + fg * 16) ^ ((fr & 7) << 4));
  int voff[4];
#pragma unroll
  for (int ni = 0; ni < 4; ++ni)
    voff[ni] = 8192 + fr * 128 + ((ni * 32 + fg * 8) ^ ((fr & 7) << 4));

  __syncthreads();   // Q, KV0, KV1 landed (vmcnt drained)

  // Q fragments -> registers; buf3 then becomes a KV buffer
  bf16x8 qa[2][2];
#pragma unroll
  for (int mi = 0; mi < 2; ++mi) {
    qa[mi][0] = *(const bf16x8*)(smem + 49152 + (qrb + mi * 16) * 128 + koff0);
    qa[mi][1] = *(const bf16x8*)(smem + 49152 + (qrb + mi * 16) * 128 + koff1);
  }
  __syncthreads();   // ALL waves' Q reads done before b3 is overwritten below

  f32x4 acco[2][4] = {};
  float lst[2] = {0.f, 0.f};

  // pair 0: stage KV2->b2, KV3->b3; compute tiles 0,1
  STAGE_K(32768, 2) STAGE_V(32768, 2) STAGE_K(49152, 3) STAGE_V(49152, 3)
  tile_pair<0, 16384>(smem, koff0, koff1, voff, qa, acco, lst);

#pragma unroll 1
  for (int pp = 1; pp <= 7; ++pp) {
    int ta = pp * 4;
    __syncthreads();                                  // b2,b3 landed; b0,b1 reads done
    STAGE_K(0, ta) STAGE_V(0, ta) STAGE_K(16384, ta + 1) STAGE_V(16384, ta + 1)
    tile_pair<32768, 49152>(smem, koff0, koff1, voff, qa, acco, lst);
    __syncthreads();                                  // b0,b1 landed; b2,b3 reads done
    STAGE_K(32768, ta + 2) STAGE_V(32768, ta + 2) STAGE_K(49152, ta + 3) STAGE_V(49152, ta + 3)
    tile_pair<0, 16384>(smem, koff0, koff1, voff, qa, acco, lst);
  }
  __syncthreads();                                    // tiles 30,31 landed
  tile_pair<32768, 49152>(smem, koff0, koff1, voff, qa, acco, lst);

  // ---- epilogue: O^T lane holds q=16mi+fr, d=16nd+4fg+reg; divide by l, 8B stores
  int b = bh >> 3, h = bh & 7;
#pragma unroll
  for (int mi = 0; mi < 2; ++mi) {
    float rl = 1.0f / lst[mi];
    int t = tt * 128 + qrb + mi * 16 + fr;
    unsigned short* rowp = attno + (size_t)(b * T_ + t) * E_ + h * 64;
#pragma unroll
    for (int nd = 0; nd < 4; ++nd) {
      ushort4 o;
      o.x = f2bf(acco[mi][nd][0] * rl);
      o.y = f2bf(acco[mi][nd][1] * rl);
      o.z = f2bf(acco[mi][nd][2] * rl);
      o.w = f2bf(acco[mi][nd][3] * rl);
      *(ushort4*)(rowp + nd * 16 + fg * 4) = o;
    }
  }
#undef STAGE_K
#undef STAGE_V
}

// ---------------------------------------------------------------- launch
extern "C" void kernel_launch(void* const* d_in, const int* in_sizes, int n_in,
                              void* d_out, int out_size, void* d_ws, size_t ws_size,
                              hipStream_t stream) {
  const float* query = (const float*)d_in[0];
  const float* key_  = (const float*)d_in[1];
  const float* value = (const float*)d_in[2];
  const float* Wq    = (const float*)d_in[3];
  const float* bq    = (const float*)d_in[4];
  const float* Wk    = (const float*)d_in[5];
  const float* bk    = (const float*)d_in[6];
  const float* Wv    = (const float*)d_in[7];
  const float* bv    = (const float*)d_in[8];
  const float* Wo    = (const float*)d_in[9];
  const float* bo    = (const float*)d_in[10];
  const float* r     = (const float*)d_in[11];

  char* ws = (char*)d_ws;
  unsigned short* qp    = (unsigned short*)(ws + 27262976);   //  8 MiB  [B,H,T,D]
  unsigned short* kp    = (unsigned short*)(ws + 35651584);   //  8 MiB  [B,H,S,D]
  unsigned short* vtp   = (unsigned short*)(ws + 44040192);   //  8 MiB  [B,H,D,S]
  unsigned short* attno = (unsigned short*)(ws + 52428800);   //  8 MiB  [B*T, E]

  const float SCLQ = 0.125f * 1.44269504089f;  // fold 1/sqrt(D) * log2(e) into Q

  // Fused fp32->bf16 staging inside the GEMMs — no separate convert pass.
  gemm_proj<<<1536, 256, 0, stream>>>(query, Wq, bq, qp,
                                      key_, Wk, bk, kp,
                                      Wv, value, bv, vtp, r, SCLQ);

  attn_flash<<<512, 256, 0, stream>>>(qp, kp, vtp, attno);

  // out = attno Wo^T + bo  (fp32)
  gemm_out<<<512, 256, 0, stream>>>(attno, Wo, bo, (float*)d_out);
}